// Round 1
// baseline (297.864 us; speedup 1.0000x reference)
//
#include <hip/hip_runtime.h>

// Problem constants (SCALE = 64, B = 4 from the reference setup_inputs).
#define SCALE_C 64
#define B_C 4
#define S2_C (SCALE_C * SCALE_C)   // 4096
#define P_C  S2_C                  // 4096 output pixels per batch

// One thread per (b, p) output pixel. Computes both warp_smpl[b,:,p] and
// warp_corr[b,:,p].
//
// Semantics derivation from the reference:
//   corr_view[b,s,p] = corr_m[b,p,s]  (permute(0,2,1))
//   gathered_i[b,p]  = corr_m[b, p, idx_i[b,p]]
//   filtered_*[b, idx_i, p] = (.set) -> LAST i writing a given idx wins.
//   warp_smpl[b,c,p] = sum over surviving i of w_i * scale_ref[b,c,idx_i]
//   warp_corr[b,c,p] = sum over surviving i of corr_m[b,p,idx_i] * scale_ref[b,c,idx_i]
__global__ void smpl_loss_pixel_kernel(const float* __restrict__ corr_m,
                                       const float* __restrict__ gt_flow,
                                       const float* __restrict__ scale_ref,
                                       float* __restrict__ out) {
    int tid = blockIdx.x * blockDim.x + threadIdx.x;
    if (tid >= B_C * P_C) return;
    int b = tid >> 12;          // / 4096
    int p = tid & (P_C - 1);    // % 4096

    // gt_grid: channel 0 -> x (col), channel 1 -> y (row)
    float gflow_x = gt_flow[(b * 2 + 0) * P_C + p];
    float gflow_y = gt_flow[(b * 2 + 1) * P_C + p];
    float gx = (gflow_x + 1.0f) * ((SCALE_C - 1) * 0.5f);
    float gy = (gflow_y + 1.0f) * ((SCALE_C - 1) * 0.5f);
    float fx = floorf(gx);
    float fy = floorf(gy);

    // offsets (ox applied to row/y, oy applied to col/x), matching reference order
    // [(0,0),(0,1),(1,0),(1,1)]
    float wy0 = fy + 1.0f - gy;   // row weight for ox=0
    float wy1 = gy - fy;          // row weight for ox=1
    float wx0 = fx + 1.0f - gx;   // col weight for oy=0
    float wx1 = gx - fx;          // col weight for oy=1

    float w[4];
    w[0] = wy0 * wx0;
    w[1] = wy0 * wx1;
    w[2] = wy1 * wx0;
    w[3] = wy1 * wx1;

    int idx[4];
    {
        float r0 = fminf(fmaxf(fy,        0.0f), (float)(SCALE_C - 1));
        float r1 = fminf(fmaxf(fy + 1.0f, 0.0f), (float)(SCALE_C - 1));
        float c0 = fminf(fmaxf(fx,        0.0f), (float)(SCALE_C - 1));
        float c1 = fminf(fmaxf(fx + 1.0f, 0.0f), (float)(SCALE_C - 1));
        idx[0] = (int)(r0 * (float)SCALE_C + c0);
        idx[1] = (int)(r0 * (float)SCALE_C + c1);
        idx[2] = (int)(r1 * (float)SCALE_C + c0);
        idx[3] = (int)(r1 * (float)SCALE_C + c1);
    }

    const float* sr = scale_ref + (size_t)b * 3 * S2_C;
    const float* cm = corr_m + (size_t)b * S2_C * S2_C + (size_t)p * S2_C;

    float s0 = 0.0f, s1 = 0.0f, s2 = 0.0f;
    float c0a = 0.0f, c1a = 0.0f, c2a = 0.0f;

    #pragma unroll
    for (int i = 0; i < 4; ++i) {
        // .set semantics: i is superseded if any later j writes the same idx
        bool include = true;
        #pragma unroll
        for (int j = i + 1; j < 4; ++j) {
            if (idx[j] == idx[i]) include = false;
        }
        if (!include) continue;
        int id = idx[i];
        float r0 = sr[0 * S2_C + id];
        float r1 = sr[1 * S2_C + id];
        float r2 = sr[2 * S2_C + id];
        float wv = w[i];
        float cv = cm[id];
        s0  += wv * r0;  s1  += wv * r1;  s2  += wv * r2;
        c0a += cv * r0;  c1a += cv * r1;  c2a += cv * r2;
    }

    // out layout: warp_smpl (B,3,64,64) then warp_corr (B,3,64,64), flat.
    float* ws_out = out;
    float* wc_out = out + (size_t)B_C * 3 * S2_C;
    ws_out[(b * 3 + 0) * S2_C + p] = s0;
    ws_out[(b * 3 + 1) * S2_C + p] = s1;
    ws_out[(b * 3 + 2) * S2_C + p] = s2;
    wc_out[(b * 3 + 0) * S2_C + p] = c0a;
    wc_out[(b * 3 + 1) * S2_C + p] = c1a;
    wc_out[(b * 3 + 2) * S2_C + p] = c2a;
}

extern "C" void kernel_launch(void* const* d_in, const int* in_sizes, int n_in,
                              void* d_out, int out_size, void* d_ws, size_t ws_size,
                              hipStream_t stream) {
    const float* corr_m    = (const float*)d_in[0];  // (4, 4096, 4096)
    const float* gt_flow   = (const float*)d_in[1];  // (4, 2, 64, 64)
    // d_in[2] = vis_mask — unused by the reference computation
    const float* scale_ref = (const float*)d_in[3];  // (4, 3, 64, 64)
    float* out = (float*)d_out;                      // 2 * (4,3,64,64) concat

    const int total = B_C * P_C;       // 16384 threads
    const int block = 64;              // one wave per block; spread over CUs
    const int grid  = (total + block - 1) / block;  // 256 blocks
    smpl_loss_pixel_kernel<<<grid, block, 0, stream>>>(corr_m, gt_flow, scale_ref, out);
}

// Round 2
// 295.839 us; speedup vs baseline: 1.0068x; 1.0068x over previous
//
#include <hip/hip_runtime.h>

// Problem constants (SCALE = 64, B = 4 from the reference setup_inputs).
#define SCALE_C 64
#define B_C 4
#define S2_C (SCALE_C * SCALE_C)   // 4096
#define P_C  S2_C                  // 4096 output pixels per batch

// One thread per (b, p) output pixel. Computes both warp_smpl[b,:,p] and
// warp_corr[b,:,p].
//
// Semantics derivation from the reference:
//   corr_view[b,s,p] = corr_m[b,p,s]  (permute(0,2,1))
//   gathered_i[b,p]  = corr_m[b, p, idx_i[b,p]]
//   filtered_*[b, idx_i, p] = (.set) -> LAST i writing a given idx wins.
//   warp_smpl[b,c,p] = sum over surviving i of w_i * scale_ref[b,c,idx_i]
//   warp_corr[b,c,p] = sum over surviving i of corr_m[b,p,idx_i] * scale_ref[b,c,idx_i]
__global__ __launch_bounds__(64) void smpl_loss_pixel_kernel(
        const float* __restrict__ corr_m,
        const float* __restrict__ gt_flow,
        const float* __restrict__ scale_ref,
        float* __restrict__ out) {
    int tid = blockIdx.x * blockDim.x + threadIdx.x;
    int b = tid >> 12;          // / 4096
    int p = tid & (P_C - 1);    // % 4096

    // gt_grid: channel 0 -> x (col), channel 1 -> y (row)
    float gflow_x = gt_flow[(b * 2 + 0) * P_C + p];
    float gflow_y = gt_flow[(b * 2 + 1) * P_C + p];
    float gx = (gflow_x + 1.0f) * ((SCALE_C - 1) * 0.5f);
    float gy = (gflow_y + 1.0f) * ((SCALE_C - 1) * 0.5f);
    float fx = floorf(gx);
    float fy = floorf(gy);

    // offsets (ox -> row/y, oy -> col/x), reference order [(0,0),(0,1),(1,0),(1,1)]
    float wy0 = fy + 1.0f - gy;
    float wy1 = gy - fy;
    float wx0 = fx + 1.0f - gx;
    float wx1 = gx - fx;

    float w[4];
    w[0] = wy0 * wx0;
    w[1] = wy0 * wx1;
    w[2] = wy1 * wx0;
    w[3] = wy1 * wx1;

    // integer clamp of neighbor coords (exactly matches float-domain clip:
    // fy/fx are integral floats in a small range)
    int iy = (int)fy, ix = (int)fx;
    int r0 = min(max(iy,     0), SCALE_C - 1);
    int r1 = min(max(iy + 1, 0), SCALE_C - 1);
    int c0 = min(max(ix,     0), SCALE_C - 1);
    int c1 = min(max(ix + 1, 0), SCALE_C - 1);

    int idx[4];
    idx[0] = r0 * SCALE_C + c0;
    idx[1] = r0 * SCALE_C + c1;
    idx[2] = r1 * SCALE_C + c0;
    idx[3] = r1 * SCALE_C + c1;

    const float* sr = scale_ref + (size_t)b * 3 * S2_C;
    const float* cm = corr_m + (size_t)b * S2_C * S2_C + (size_t)p * S2_C;

    // Issue ALL scattered loads up front (max memory-level parallelism),
    // then resolve dedup + accumulate.
    float sr0[4], sr1[4], sr2[4], cv[4];
    #pragma unroll
    for (int i = 0; i < 4; ++i) {
        int id = idx[i];
        sr0[i] = sr[0 * S2_C + id];
        sr1[i] = sr[1 * S2_C + id];
        sr2[i] = sr[2 * S2_C + id];
        cv[i]  = cm[id];
    }

    float s0 = 0.0f, s1 = 0.0f, s2 = 0.0f;
    float c0a = 0.0f, c1a = 0.0f, c2a = 0.0f;
    #pragma unroll
    for (int i = 0; i < 4; ++i) {
        // .set semantics: entry i is superseded if any later j writes same idx
        bool include = true;
        #pragma unroll
        for (int j = i + 1; j < 4; ++j) {
            if (idx[j] == idx[i]) include = false;
        }
        float m = include ? 1.0f : 0.0f;  // predicated, no divergence
        float wv = w[i] * m;
        float cw = cv[i] * m;
        s0  = fmaf(wv, sr0[i], s0);
        s1  = fmaf(wv, sr1[i], s1);
        s2  = fmaf(wv, sr2[i], s2);
        c0a = fmaf(cw, sr0[i], c0a);
        c1a = fmaf(cw, sr1[i], c1a);
        c2a = fmaf(cw, sr2[i], c2a);
    }

    // out layout: warp_smpl (B,3,64,64) then warp_corr (B,3,64,64), flat.
    float* ws_out = out;
    float* wc_out = out + (size_t)B_C * 3 * S2_C;
    ws_out[(b * 3 + 0) * S2_C + p] = s0;
    ws_out[(b * 3 + 1) * S2_C + p] = s1;
    ws_out[(b * 3 + 2) * S2_C + p] = s2;
    wc_out[(b * 3 + 0) * S2_C + p] = c0a;
    wc_out[(b * 3 + 1) * S2_C + p] = c1a;
    wc_out[(b * 3 + 2) * S2_C + p] = c2a;
}

extern "C" void kernel_launch(void* const* d_in, const int* in_sizes, int n_in,
                              void* d_out, int out_size, void* d_ws, size_t ws_size,
                              hipStream_t stream) {
    const float* corr_m    = (const float*)d_in[0];  // (4, 4096, 4096)
    const float* gt_flow   = (const float*)d_in[1];  // (4, 2, 64, 64)
    // d_in[2] = vis_mask — unused by the reference computation
    const float* scale_ref = (const float*)d_in[3];  // (4, 3, 64, 64)
    float* out = (float*)d_out;                      // 2 * (4,3,64,64) concat

    const int total = B_C * P_C;       // 16384 threads
    const int block = 64;              // one wave per block; max CU spread
    const int grid  = total / block;   // 256 blocks
    smpl_loss_pixel_kernel<<<grid, block, 0, stream>>>(corr_m, gt_flow, scale_ref, out);
}